// Round 2
// baseline (1565.053 us; speedup 1.0000x reference)
//
#include <hip/hip_runtime.h>
#include <hip/hip_cooperative_groups.h>
#include <stdint.h>

namespace cg = cooperative_groups;

// Problem constants (from reference): B=4, S=4096, D=2, 3 RK2 steps.
#define BATCH   4
#define SEQ     4096
#define WPR     64                  // 64-bit bitmask words per row (SEQ/64)
#define NROWS   (BATCH * SEQ)       // 16384
#define DTS     0.1f
#define HALF_DT 0.05f
#define EPS     1e-8f

#define NBLOCK  1024                // 4 blocks/CU -> cooperative co-residency safe
#define NTHR    256
#define NWAVES  (NBLOCK * NTHR / 64)    // 4096 waves
#define ROWS_PER_WAVE (NROWS / NWAVES)  // 4

// Row force-sum: lane l owns bitmask word l (coalesced 8B/lane). Bit j of
// word l maps to col = (l>>2)*256 + 4*j + (l&3)  (ballot-interleaved layout
// produced by the compress phase). Gathers are 8B float2 within a 32KB
// batch window (L1-resident). 64-lane xor-butterfly reduces to all lanes.
__device__ __forceinline__ float2 row_force_sum(
        const unsigned long long* __restrict__ bits,
        const float2* __restrict__ gbatch, int row, int lane) {
    unsigned long long w = bits[(size_t)row * WPR + lane];
    const int colbase = ((lane >> 2) << 8) | (lane & 3);
    float sx = 0.f, sy = 0.f;
    while (w) {
        int j = __builtin_ctzll(w);
        w &= (w - 1);
        float2 v = gbatch[colbase + (j << 2)];
        sx += v.x; sy += v.y;
    }
#pragma unroll
    for (int m = 32; m >= 1; m >>= 1) {
        sx += __shfl_xor(sx, m, 64);
        sy += __shfl_xor(sy, m, 64);
    }
    return make_float2(sx, sy);
}

__global__ __launch_bounds__(NTHR, 4)
void fused_rdi(const float* __restrict__ mask,
               const float2* __restrict__ psi,
               unsigned long long* __restrict__ bits,
               float2* __restrict__ pbuf,
               float2* __restrict__ k1buf,
               float2* __restrict__ starbuf,
               float*  __restrict__ rbuf,
               float2* __restrict__ out) {
    cg::grid_group grid = cg::this_grid();
    const int wave = (blockIdx.x * NTHR + threadIdx.x) >> 6;
    const int lane = threadIdx.x & 63;

    // ---- Phase 0: compress fp32 mask -> bitmask via ballot -------------
    // Lane l loads float4 at contiguous addresses (1KB/wave-inst, coalesced).
    // ballot over component c of chunk k forms word (k*4+c); the lane whose
    // id equals that word index keeps it, then one coalesced 8B store/row.
    for (int i = 0; i < ROWS_PER_WAVE; ++i) {
        const int row = wave * ROWS_PER_WAVE + i;
        const float4* src = reinterpret_cast<const float4*>(mask + (size_t)row * SEQ);
        unsigned long long word = 0ull;
#pragma unroll
        for (int c = 0; c < 16; ++c) {
            float4 v = src[c * 64 + lane];
            unsigned long long b;
            b = __ballot(v.x != 0.f); word = (lane == c * 4 + 0) ? b : word;
            b = __ballot(v.y != 0.f); word = (lane == c * 4 + 1) ? b : word;
            b = __ballot(v.z != 0.f); word = (lane == c * 4 + 2) ? b : word;
            b = __ballot(v.w != 0.f); word = (lane == c * 4 + 3) ? b : word;
        }
        bits[(size_t)row * WPR + lane] = word;
    }

    __threadfence();
    grid.sync();

    // ---- 3 RK2 steps, 2 force phases each, grid.sync between phases ----
    for (int s = 0; s < 3; ++s) {
        const float2* pIn  = (s == 0) ? psi : pbuf;
        float2*       pOut = (s == 2) ? out : pbuf;

        // Phase A: k1 = M@p - p; star = renorm(p + DT*k1, r)
        for (int i = 0; i < ROWS_PER_WAVE; ++i) {
            const int row = wave * ROWS_PER_WAVE + i;
            const int b = row >> 12;
            float2 sum = row_force_sum(bits, pIn + ((size_t)b << 12), row, lane);
            float2 p = pIn[row];
            float r   = sqrtf(p.x * p.x + p.y * p.y);
            float k1x = sum.x - p.x, k1y = sum.y - p.y;
            float tx  = p.x + DTS * k1x, ty = p.y + DTS * k1y;
            float sc  = r / (sqrtf(tx * tx + ty * ty) + EPS);
            if (lane == 0) {
                k1buf[row]   = make_float2(k1x, k1y);
                starbuf[row] = make_float2(tx * sc, ty * sc);
                rbuf[row]    = r;
            }
        }

        __threadfence();
        grid.sync();

        // Phase B: k2 = M@star - star; p_new = renorm(p + DT/2*(k1+k2), r)
        for (int i = 0; i < ROWS_PER_WAVE; ++i) {
            const int row = wave * ROWS_PER_WAVE + i;
            const int b = row >> 12;
            float2 sum = row_force_sum(bits, starbuf + ((size_t)b << 12), row, lane);
            float2 st = starbuf[row];
            float2 p  = pIn[row];
            float2 k1 = k1buf[row];
            float k2x = sum.x - st.x, k2y = sum.y - st.y;
            float nx  = p.x + HALF_DT * (k1.x + k2x);
            float ny  = p.y + HALF_DT * (k1.y + k2y);
            float sc  = rbuf[row] / (sqrtf(nx * nx + ny * ny) + EPS);
            if (lane == 0) pOut[row] = make_float2(nx * sc, ny * sc);
        }

        if (s < 2) {
            __threadfence();
            grid.sync();
        }
    }
}

extern "C" void kernel_launch(void* const* d_in, const int* in_sizes, int n_in,
                              void* d_out, int out_size, void* d_ws, size_t ws_size,
                              hipStream_t stream) {
    const float* psi  = (const float*)d_in[0];   // [4,4096,2] fp32
    const float* mask = (const float*)d_in[1];   // [4,4096,4096] fp32 (0/1)
    float2* out2 = (float2*)d_out;               // [4,4096,2] fp32

    // Workspace layout: bitmask 8 MB | p 128 KB | k1 128 KB | star 128 KB | r 64 KB
    char* ws = (char*)d_ws;
    unsigned long long* bits = (unsigned long long*)ws;
    float2* p    = (float2*)(ws + (size_t)NROWS * WPR * 8);
    float2* k1   = p + NROWS;
    float2* star = k1 + NROWS;
    float*  rbuf = (float*)(star + NROWS);

    const float2* psi2 = (const float2*)psi;

    void* args[] = { (void*)&mask, (void*)&psi2, (void*)&bits, (void*)&p,
                     (void*)&k1, (void*)&star, (void*)&rbuf, (void*)&out2 };
    hipLaunchCooperativeKernel((void*)fused_rdi, dim3(NBLOCK), dim3(NTHR),
                               args, 0, stream);
}

// Round 3
// 394.194 us; speedup vs baseline: 3.9703x; 3.9703x over previous
//
#include <hip/hip_runtime.h>
#include <stdint.h>

// Problem constants (from reference): B=4, S=4096, D=2, 3 RK2 steps.
#define BATCH   4
#define SEQ     4096
#define WPR     64                  // 64-bit bitmask words per row (SEQ/64)
#define NROWS   (BATCH * SEQ)       // 16384
#define DTS     0.1f
#define HALF_DT 0.05f
#define EPS     1e-8f

// Bitmask layout (ballot-interleaved): word w of a row holds, at bit j, the
// mask entry for column col = (w>>2)*256 + 4*j + (w&3). Produced by ballots
// over float4 components; consumed with colbase = ((w>>2)<<8)|(w&3).
__device__ __forceinline__ float2 ballot_force_sum(unsigned long long w,
                                                   const float2* __restrict__ gb,
                                                   int lane) {
    const int colbase = ((lane >> 2) << 8) | (lane & 3);
    float sx = 0.f, sy = 0.f;
    while (w) {
        int j = __builtin_ctzll(w);
        w &= (w - 1);
        float2 v = gb[colbase + (j << 2)];
        sx += v.x; sy += v.y;
    }
#pragma unroll
    for (int m = 32; m >= 1; m >>= 1) {
        sx += __shfl_xor(sx, m, 64);
        sy += __shfl_xor(sy, m, 64);
    }
    return make_float2(sx, sy);
}

// ---------------------------------------------------------------------------
// Kernel 1: compress + step-1 phase A, fused. Wave-per-row (16384 waves).
// Lane l loads contiguous float4 (1 KB/wave-inst, perfectly coalesced);
// __ballot packs 64 mask entries into an SGPR word; lane l keeps word l.
// Phase A needs only this row's bits (in registers) and gathers from the
// INPUT psi — no global sync required, so it rides along for free.
// ---------------------------------------------------------------------------
__global__ __launch_bounds__(256)
void compress_phaseA(const float* __restrict__ mask,
                     const float2* __restrict__ psi,
                     unsigned long long* __restrict__ bits,
                     float2* __restrict__ k1buf,
                     float2* __restrict__ starbuf,
                     float*  __restrict__ rbuf) {
    const int row  = (blockIdx.x * blockDim.x + threadIdx.x) >> 6;
    const int lane = threadIdx.x & 63;

    const float4* src = reinterpret_cast<const float4*>(mask + (size_t)row * SEQ);
    unsigned long long word = 0ull;
#pragma unroll
    for (int c = 0; c < 16; ++c) {
        float4 v = src[c * 64 + lane];
        unsigned long long b;
        b = __ballot(v.x != 0.f); if (lane == c * 4 + 0) word = b;
        b = __ballot(v.y != 0.f); if (lane == c * 4 + 1) word = b;
        b = __ballot(v.z != 0.f); if (lane == c * 4 + 2) word = b;
        b = __ballot(v.w != 0.f); if (lane == c * 4 + 3) word = b;
    }
    bits[(size_t)row * WPR + lane] = word;       // coalesced 8B/lane

    // --- step-1 phase A, using the word still in registers ---
    const int bidx = row >> 12;
    float2 sum = ballot_force_sum(word, psi + ((size_t)bidx << 12), lane);
    float2 p  = psi[row];
    float r   = sqrtf(p.x * p.x + p.y * p.y);
    float k1x = sum.x - p.x, k1y = sum.y - p.y;
    float tx  = p.x + DTS * k1x, ty = p.y + DTS * k1y;
    float sc  = r / (sqrtf(tx * tx + ty * ty) + EPS);
    if (lane == 0) {
        k1buf[row]   = make_float2(k1x, k1y);
        starbuf[row] = make_float2(tx * sc, ty * sc);
        rbuf[row]    = r;
    }
}

// ---------------------------------------------------------------------------
// Force + RK2-stage update (steps after the first phase). Wave-per-row.
// PHASE 0: k1 = M@p - p; star = renorm(p + DT*k1, r);  writes k1,star,r.
// PHASE 1: k2 = M@star - star; p_new = renorm(p + DT/2*(k1+k2), r) -> outbuf.
// ---------------------------------------------------------------------------
template <int PHASE>
__global__ __launch_bounds__(256)
void force_step(const unsigned long long* __restrict__ bits,
                const float2* __restrict__ pIn,     // current state
                const float2* __restrict__ gsrc,    // gather source (p or star)
                float2* __restrict__ k1buf,
                float2* __restrict__ starbuf,
                float*  __restrict__ rbuf,
                float2* __restrict__ outbuf) {
    const int row  = (blockIdx.x * blockDim.x + threadIdx.x) >> 6;
    const int lane = threadIdx.x & 63;
    const int bidx = row >> 12;

    unsigned long long w = bits[(size_t)row * WPR + lane];
    float2 sum = ballot_force_sum(w, gsrc + ((size_t)bidx << 12), lane);

    if (lane == 0) {
        if (PHASE == 0) {
            float2 p = pIn[row];
            float r   = sqrtf(p.x * p.x + p.y * p.y);
            float k1x = sum.x - p.x, k1y = sum.y - p.y;
            float tx  = p.x + DTS * k1x, ty = p.y + DTS * k1y;
            float sc  = r / (sqrtf(tx * tx + ty * ty) + EPS);
            k1buf[row]   = make_float2(k1x, k1y);
            starbuf[row] = make_float2(tx * sc, ty * sc);
            rbuf[row]    = r;
        } else {
            float2 st = gsrc[row];                 // psi_star (self)
            float k2x = sum.x - st.x, k2y = sum.y - st.y;
            float2 p  = pIn[row];
            float2 k1 = k1buf[row];
            float nx  = p.x + HALF_DT * (k1.x + k2x);
            float ny  = p.y + HALF_DT * (k1.y + k2y);
            float sc  = rbuf[row] / (sqrtf(nx * nx + ny * ny) + EPS);
            outbuf[row] = make_float2(nx * sc, ny * sc);
        }
    }
}

extern "C" void kernel_launch(void* const* d_in, const int* in_sizes, int n_in,
                              void* d_out, int out_size, void* d_ws, size_t ws_size,
                              hipStream_t stream) {
    const float* psi  = (const float*)d_in[0];   // [4,4096,2] fp32
    const float* mask = (const float*)d_in[1];   // [4,4096,4096] fp32 (0/1)
    float2* out2 = (float2*)d_out;               // [4,4096,2] fp32

    // Workspace layout: bitmask 8 MB | p 128 KB | k1 128 KB | star 128 KB | r 64 KB
    char* ws = (char*)d_ws;
    unsigned long long* bits = (unsigned long long*)ws;
    float2* p    = (float2*)(ws + (size_t)NROWS * WPR * 8);
    float2* k1   = p + NROWS;
    float2* star = k1 + NROWS;
    float*  rbuf = (float*)(star + NROWS);

    const float2* psi2 = (const float2*)psi;
    const int grid = NROWS / 4;                  // 4 waves (rows) per 256-thr block

    // step 1: compress + phase A fused; then phase B -> p
    compress_phaseA<<<grid, 256, 0, stream>>>(mask, psi2, bits, k1, star, rbuf);
    force_step<1><<<grid, 256, 0, stream>>>(bits, psi2, star, k1, star, rbuf, p);
    // step 2 (in-place p update; PHASE 1 only reads its own p[row])
    force_step<0><<<grid, 256, 0, stream>>>(bits, p, p, k1, star, rbuf, nullptr);
    force_step<1><<<grid, 256, 0, stream>>>(bits, p, star, k1, star, rbuf, p);
    // step 3 (writes final state straight to d_out)
    force_step<0><<<grid, 256, 0, stream>>>(bits, p, p, k1, star, rbuf, nullptr);
    force_step<1><<<grid, 256, 0, stream>>>(bits, p, star, k1, star, rbuf, out2);
}